// Round 13
// baseline (255.070 us; speedup 1.0000x reference)
//
#include <hip/hip_runtime.h>
#include <hip/hip_cooperative_groups.h>
#include <math.h>

namespace cg = cooperative_groups;

#define DEV __device__ __forceinline__
typedef _Float16 h16;
typedef __attribute__((ext_vector_type(8))) _Float16 h8v;  // 8 fp16 = 4 VGPR
typedef __attribute__((ext_vector_type(4))) _Float16 h4v;  // 8-byte fp16 store
typedef __attribute__((ext_vector_type(4))) float f4v;

constexpr int NTOK = 1024;
constexpr int D    = 512;
constexpr double EPSd = 1e-7;

struct KParams {
  const float *x, *cgl, *Wqkv, *bqkv, *Wout, *bout, *s1, *b1, *s2, *b2;
  const float *Wff1, *bff1, *Wff2, *bff2, *chl, *geo;
  float* out;
  h16 *WqkvT, *WoutT, *Wff1T, *Wff2T, *xt, *qkv, *ao, *t2, *h1;
  float *proj, *xa, *f2;
};

// ---------------- wave reduction ----------------
DEV double wave_sum(double v) {
#pragma unroll
  for (int m = 32; m; m >>= 1) v += __shfl_xor(v, m, 64);
  return v;
}

// ---------------- 64x64 transpose-cast tile: fp32[K][N] -> fp16[N][K] ----------------
DEV void tcast64(const float* __restrict__ src, h16* __restrict__ dst,
                 int K, int N, int n0, int k0, float* tls /* [64*68] */) {
  const int tx = threadIdx.x & 15, ty = threadIdx.x >> 4;
#pragma unroll
  for (int it = 0; it < 4; ++it) {
    const int k = ty + it * 16;
    float4 v = *(const float4*)(src + (size_t)(k0 + k) * N + n0 + tx * 4);
    *(float4*)(tls + k * 68 + tx * 4) = v;
  }
  __syncthreads();
#pragma unroll
  for (int it = 0; it < 4; ++it) {
    const int n = ty + it * 16;
    const int kc = tx * 4;
    h4v o;
#pragma unroll
    for (int j = 0; j < 4; ++j) o[j] = (h16)tls[(kc + j) * 68 + n];
    *(h4v*)(dst + (size_t)(n0 + n) * K + k0 + kc) = o;
  }
}

// ---------------- pre: logmap0 -> LN -> expmap0 -> logmap0 (fused), one WAVE per row --------
DEV void do_pre(int pb, const KParams& p) {
  const int wid = threadIdx.x >> 6, lane = threadIdx.x & 63;
  const int tok = pb * 4 + wid;
  const float4* xr = (const float4*)(p.x + (size_t)tok * D);
  float4 xv0 = xr[lane], xv1 = xr[lane + 64];
  double sv = 0.0, svv = 0.0;
  {
    const float e[8] = {xv0.x, xv0.y, xv0.z, xv0.w, xv1.x, xv1.y, xv1.z, xv1.w};
#pragma unroll
    for (int j = 0; j < 8; ++j) { double d = e[j]; sv += d; svv += d * d; }
  }
  sv = wave_sum(sv); svv = wave_sum(svv);
  double c = (double)p.cgl[0];
  double sc = sqrt(c); if (sc < EPSd) sc = EPSd;
  double yn = sqrt(svv);
  double arg0 = yn; if (arg0 > 1.0 - EPSd) arg0 = 1.0 - EPSd;
  double f = (yn < EPSd) ? 0.0 : atanh(arg0) / sc / fmax(yn, EPSd);
  double mu = f * sv / D;
  double var = f * f * svv / D - mu * mu;
  double rs = 1.0 / sqrt(var + 1e-6);
  const float4* s1r = (const float4*)p.s1;
  const float4* b1r = (const float4*)p.b1;
  float4 sA = s1r[lane], sB = s1r[lane + 64];
  float4 bA = b1r[lane], bB = b1r[lane + 64];
  double w[8]; double sww = 0.0;
  {
    const float e[8]  = {xv0.x, xv0.y, xv0.z, xv0.w, xv1.x, xv1.y, xv1.z, xv1.w};
    const float se[8] = {sA.x, sA.y, sA.z, sA.w, sB.x, sB.y, sB.z, sB.w};
    const float be[8] = {bA.x, bA.y, bA.z, bA.w, bB.x, bB.y, bB.z, bB.w};
#pragma unroll
    for (int j = 0; j < 8; ++j) {
      w[j] = (f * (double)e[j] - mu) * rs * (double)se[j] + (double)be[j];
      sww += w[j] * w[j];
    }
  }
  sww = wave_sum(sww);
  double vn = sqrt(sww);
  double F = 0.0;
  if (vn >= EPSd) {
    double mag_e = tanh(sc * fmax(vn, EPSd)) / sc;
    F = atanh(fmin(mag_e, 1.0 - EPSd)) / (sc * vn);
  }
  h16* dst = p.xt + (size_t)tok * D;
#pragma unroll
  for (int half = 0; half < 2; ++half) {
    h4v o;
#pragma unroll
    for (int e = 0; e < 4; ++e) o[e] = (h16)(float)(F * w[half * 4 + e]);
    *(h4v*)(dst + 4 * (lane + 64 * half)) = o;
  }
}

// ---------------- fp16 MFMA GEMM body, 64x64 tile, BK=64, 3-deep counted-vmcnt --------------
DEV void stage_tile(const h16* __restrict__ gbase, int rowstride, h16* lds,
                    int wid, int lane) {
#pragma unroll
  for (int j = 0; j < 2; ++j) {
    const int rbase = wid * 16 + j * 8;
    const int grow = rbase + (lane >> 3);
    const int gch = (lane & 7) ^ (lane >> 3);
    const h16* gp = gbase + (size_t)grow * rowstride + gch * 8;
    __builtin_amdgcn_global_load_lds(
        (const __attribute__((address_space(1))) void*)gp,
        (__attribute__((address_space(3))) void*)(lds + rbase * 64), 16, 0, 0);
  }
}
DEV h8v read_frag(const h16* lds, int row, int c) {
  const int p = c ^ (row & 7);
  return *(const h8v*)(lds + row * 64 + p * 8);
}

// SPLITK: kz piece over K/2; piece kz writes Cf + kz*M*N (fp32), bias only in piece 0.
template <int GELU, int OHALF, int SPLITK>
DEV void mm_body(h16* AsB, h16* BsB,
                 const h16* __restrict__ A, const h16* __restrict__ B,
                 const float* __restrict__ bias, float* __restrict__ Cf,
                 h16* __restrict__ Ch, int M, int N, int K, int bxx, int byy, int kz) {
  const int tid = threadIdx.x;
  const int lane = tid & 63, wid = tid >> 6;
  const int wr = (wid >> 1) * 32, wc = (wid & 1) * 32;
  const int lr = lane & 15, lg = lane >> 4;
  const size_t r0 = (size_t)byy * 64, c0 = (size_t)bxx * 64;
  const int Keff = SPLITK ? (K >> 1) : K;
  const f4v z = {0.f, 0.f, 0.f, 0.f};
  f4v acc[2][2]; acc[0][0] = z; acc[0][1] = z; acc[1][0] = z; acc[1][1] = z;
  const h16* Abase = A + r0 * K + (size_t)kz * Keff;
  const h16* Bbase = B + c0 * K + (size_t)kz * Keff;
  const int NT = Keff >> 6;
  // Pin the vmcnt protocol: preload bias, then drain ALL outstanding VMEM (incl. any
  // fire-and-forget stores from a previous phase) so counted waits below are exact.
  const size_t col0 = c0 + wc + lr;
  float bv0 = bias[col0];
  float bv1 = bias[col0 + 16];
  asm volatile("" :: "v"(bv0), "v"(bv1));             // force loads issued here
  asm volatile("s_waitcnt vmcnt(0)" ::: "memory");    // zero outstanding VMEM
  if (SPLITK && kz) { bv0 = 0.f; bv1 = 0.f; }
  // prologue: tiles 0,1 in flight (8 loads/wave)
  stage_tile(Abase, K, AsB, wid, lane);
  stage_tile(Bbase, K, BsB, wid, lane);
  stage_tile(Abase + 64, K, AsB + 4096, wid, lane);
  stage_tile(Bbase + 64, K, BsB + 4096, wid, lane);
  int cur = 0;
  for (int t = 0; t < NT; ++t) {
    const int pre = (cur == 2) ? 0 : cur + 1;
    const int pre2 = (pre == 2) ? 0 : pre + 1;
    if (t + 2 < NT) {                      // keep 2 tiles in flight
      stage_tile(Abase + (t + 2) * 64, K, AsB + pre2 * 4096, wid, lane);
      stage_tile(Bbase + (t + 2) * 64, K, BsB + pre2 * 4096, wid, lane);
    }
    const int rem = NT - 1 - t;
    if (rem >= 2)      asm volatile("s_waitcnt vmcnt(8)" ::: "memory");
    else if (rem == 1) asm volatile("s_waitcnt vmcnt(4)" ::: "memory");
    else               asm volatile("s_waitcnt vmcnt(0)" ::: "memory");
    asm volatile("s_barrier" ::: "memory");             // all waves' cur loads landed
    const h16* Ac = AsB + cur * 4096;
    const h16* Bc = BsB + cur * 4096;
#pragma unroll
    for (int ks = 0; ks < 2; ++ks) {
      const int c = ks * 4 + lg;
      h8v a0 = read_frag(Ac, wr + lr, c);
      h8v a1 = read_frag(Ac, wr + 16 + lr, c);
      h8v b0 = read_frag(Bc, wc + lr, c);
      h8v b1 = read_frag(Bc, wc + 16 + lr, c);
      acc[0][0] = __builtin_amdgcn_mfma_f32_16x16x32_f16(a0, b0, acc[0][0], 0, 0, 0);
      acc[0][1] = __builtin_amdgcn_mfma_f32_16x16x32_f16(a0, b1, acc[0][1], 0, 0, 0);
      acc[1][0] = __builtin_amdgcn_mfma_f32_16x16x32_f16(a1, b0, acc[1][0], 0, 0, 0);
      acc[1][1] = __builtin_amdgcn_mfma_f32_16x16x32_f16(a1, b1, acc[1][1], 0, 0, 0);
    }
    asm volatile("s_barrier" ::: "memory");
    cur = pre;
  }
  float* Cfo = Cf + (size_t)kz * M * N;
#pragma unroll
  for (int m = 0; m < 2; ++m)
#pragma unroll
    for (int n = 0; n < 2; ++n) {
      const size_t row = r0 + wr + m * 16 + lg * 4;
      const size_t col = col0 + n * 16;
      const float bv = n ? bv1 : bv0;
#pragma unroll
      for (int e = 0; e < 4; ++e) {
        float v = acc[m][n][e] + bv;
        if (GELU) {
          float x3 = v * v * v;
          v = 0.5f * v * (1.0f + tanhf(0.7978845608028654f * (v + 0.044715f * x3)));
        }
        if (OHALF) Ch[(row + e) * N + col] = (h16)v;
        else       Cfo[(row + e) * N + col] = v;
      }
    }
}

// ---------------- attention: RoPE + per-head expmap0 + hyperbolic dist + softmax + PV -------
DEV void do_attn(int bid, const KParams& p, char* SM) {
  float (*Qs)[68] = (float(*)[68])SM;              // 8704 B
  float (*Kt)[68] = (float(*)[68])(SM + 8704);     // 17408 B
  float (*Vs)[68] = (float(*)[68])(SM + 26112);    // 17408 B
  float* q2raw = (float*)(SM + 43520);
  float* k2raw = (float*)(SM + 43648);
  float* q2s   = (float*)(SM + 43904);
  float* k2s   = (float*)(SM + 44032);
  float* fqv   = (float*)(SM + 44288);
  float* fkv   = (float*)(SM + 44416);             // ends 44672 < 49152
  const int be = bid >> 4, h = (bid >> 1) & 7, q0 = (bid & 1) * 32;
  const int tid = threadIdx.x;
  const double chd = log1p(exp((double)p.chl[h]));   // softplus
  const float ch = (float)chd;
  float sc = (float)sqrt(chd); if (sc < 1e-7f) sc = 1e-7f;
  __syncthreads();                                 // LDS arena handoff
  // ---- stage K^T (RoPE) + V, 64 rows; 256 tasks ----
  {
    const int s = tid >> 2, jc = (tid & 3) * 8;
    const h16* base = p.qkv + (size_t)(be * 64 + s) * 1536 + h * 64;
    h8v klo = *(const h8v*)(base + 512 + jc);
    h8v khi = *(const h8v*)(base + 512 + jc + 32);
    h8v vlo = *(const h8v*)(base + 1024 + jc);
    h8v vhi = *(const h8v*)(base + 1024 + jc + 32);
    float racc = 0.f;
#pragma unroll
    for (int j = 0; j < 8; ++j) {
      float ka = (float)klo[j], kb = (float)khi[j];
      racc += ka * ka + kb * kb;
      float fj = expf((float)(jc + j) * -0.2878231366242557f);   // ln(10000)/32
      float st, ct; sincosf((float)s * fj, &st, &ct);
      Kt[jc + j][s]      = ka * ct - kb * st;
      Kt[jc + j + 32][s] = ka * st + kb * ct;
    }
    float4 v0, v1;
#pragma unroll
    for (int j = 0; j < 4; ++j) { v0[j] = (float)vlo[j]; v1[j] = (float)vlo[j + 4]; }
    *(float4*)&Vs[s][jc] = v0; *(float4*)&Vs[s][jc + 4] = v1;
#pragma unroll
    for (int j = 0; j < 4; ++j) { v0[j] = (float)vhi[j]; v1[j] = (float)vhi[j + 4]; }
    *(float4*)&Vs[s][jc + 32] = v0; *(float4*)&Vs[s][jc + 36] = v1;
    racc += __shfl_xor(racc, 1, 64);
    racc += __shfl_xor(racc, 2, 64);
    if ((tid & 3) == 0) k2raw[s] = racc;
  }
  // ---- stage Q (RoPE), 32 rows; 128 tasks ----
  if (tid < 128) {
    const int s = tid >> 2, jc = (tid & 3) * 8;
    const h16* base = p.qkv + (size_t)(be * 64 + q0 + s) * 1536 + h * 64;
    h8v qlo = *(const h8v*)(base + jc);
    h8v qhi = *(const h8v*)(base + jc + 32);
    float racc = 0.f;
    float rl[8], rh[8];
#pragma unroll
    for (int j = 0; j < 8; ++j) {
      float qa = (float)qlo[j], qb = (float)qhi[j];
      racc += qa * qa + qb * qb;
      float fj = expf((float)(jc + j) * -0.2878231366242557f);
      float st, ct; sincosf((float)(q0 + s) * fj, &st, &ct);
      rl[j] = qa * ct - qb * st;
      rh[j] = qa * st + qb * ct;
    }
    *(float4*)&Qs[s][jc]      = {rl[0], rl[1], rl[2], rl[3]};
    *(float4*)&Qs[s][jc + 4]  = {rl[4], rl[5], rl[6], rl[7]};
    *(float4*)&Qs[s][jc + 32] = {rh[0], rh[1], rh[2], rh[3]};
    *(float4*)&Qs[s][jc + 36] = {rh[4], rh[5], rh[6], rh[7]};
    racc += __shfl_xor(racc, 1, 64);
    racc += __shfl_xor(racc, 2, 64);
    if ((tid & 3) == 0) q2raw[s] = racc;
  }
  __syncthreads();
  // ---- per-row expmap0 factors from raw norms (RoPE is orthogonal) ----
  if (tid < 64) {
    float n = sqrtf(k2raw[tid]);
    float m = tanhf(sc * fmaxf(n, 1e-7f)) / sc;
    float f = (n < 1e-7f) ? 0.f : m / fmaxf(n, 1e-7f);
    if (m >= 1.f) f *= (1.f - 1e-7f) / m;
    float fn = f * n;
    fkv[tid] = f; k2s[tid] = fn * fn;
  } else if (tid < 96) {
    int i = tid - 64;
    float n = sqrtf(q2raw[i]);
    float m = tanhf(sc * fmaxf(n, 1e-7f)) / sc;
    float f = (n < 1e-7f) ? 0.f : m / fmaxf(n, 1e-7f);
    if (m >= 1.f) f *= (1.f - 1e-7f) / m;
    float fn = f * n;
    fqv[i] = f; q2s[i] = fn * fn;
  }
  __syncthreads();
  const int i = tid >> 3, g = tid & 7;   // local q-row, 8-col group
  float gacc[8];
#pragma unroll
  for (int jj = 0; jj < 8; ++jj) gacc[jj] = 0.f;
  for (int d2 = 0; d2 < 64; ++d2) {
    float qv = Qs[i][d2];
    const float4* kp = (const float4*)&Kt[d2][g * 8];
    float4 k0 = kp[0], k1 = kp[1];
    gacc[0] += qv * k0.x; gacc[1] += qv * k0.y; gacc[2] += qv * k0.z; gacc[3] += qv * k0.w;
    gacc[4] += qv * k1.x; gacc[5] += qv * k1.y; gacc[6] += qv * k1.z; gacc[7] += qv * k1.w;
  }
  const float gs = p.geo[h];
  const float q2 = q2s[i], fqi = fqv[i];
  float lg[8];
  float mx = -1e30f;
#pragma unroll
  for (int jj = 0; jj < 8; ++jj) {
    float gq = fqi * fkv[g * 8 + jj] * gacc[jj];
    float k2 = k2s[g * 8 + jj];
    float A  = 1.f - 2.f * ch * gq + ch * k2;
    float Bv = 1.f - ch * q2;
    float n2 = fmaxf(A * A * q2 - 2.f * A * Bv * gq + Bv * Bv * k2, 0.f);
    float den = fmaxf(1.f - 2.f * ch * gq + ch * ch * q2 * k2, 1e-7f);
    float r = fminf(sqrtf(n2) / den, 1.f - 1e-7f);
    float arg = fminf(sc * r, 1.f - 1e-7f);
    float l = -gs * (2.f * atanhf(arg) / sc);
    lg[jj] = l; mx = fmaxf(mx, l);
  }
  mx = fmaxf(mx, __shfl_xor(mx, 1, 64));
  mx = fmaxf(mx, __shfl_xor(mx, 2, 64));
  mx = fmaxf(mx, __shfl_xor(mx, 4, 64));
  float pv[8]; float sum = 0.f;
#pragma unroll
  for (int jj = 0; jj < 8; ++jj) { pv[jj] = expf(lg[jj] - mx); sum += pv[jj]; }
  sum += __shfl_xor(sum, 1, 64);
  sum += __shfl_xor(sum, 2, 64);
  sum += __shfl_xor(sum, 4, 64);
  float inv = 1.0f / sum;
  // P overwrite of Qs: wave w owns rows 8w..8w+7 exclusively; in-wave lockstep safe.
#pragma unroll
  for (int jj = 0; jj < 8; ++jj) Qs[i][g * 8 + jj] = pv[jj] * inv;
  float oacc[8];
#pragma unroll
  for (int dd = 0; dd < 8; ++dd) oacc[dd] = 0.f;
  for (int jv = 0; jv < 64; ++jv) {
    float ppv = Qs[i][jv];
    const float4* vp = (const float4*)&Vs[jv][g * 8];
    float4 v0 = vp[0], v1 = vp[1];
    oacc[0] += ppv * v0.x; oacc[1] += ppv * v0.y; oacc[2] += ppv * v0.z; oacc[3] += ppv * v0.w;
    oacc[4] += ppv * v1.x; oacc[5] += ppv * v1.y; oacc[6] += ppv * v1.z; oacc[7] += ppv * v1.w;
  }
  h8v ov;
#pragma unroll
  for (int dd = 0; dd < 8; ++dd) ov[dd] = (h16)oacc[dd];
  *(h8v*)(p.ao + (size_t)(be * 64 + q0 + i) * D + h * 64 + g * 8) = ov;
}

// ---------------- residual: expmap0(proj) -> mobius add -> LN2 chain; one WAVE per row ------
DEV void do_resid(int pb, const KParams& p) {
  const int wid = threadIdx.x >> 6, lane = threadIdx.x & 63;
  const int tok = pb * 4 + wid;
  const float4* xr  = (const float4*)(p.x + (size_t)tok * D);
  const float4* p0r = (const float4*)(p.proj + (size_t)tok * D);
  const float4* p1r = (const float4*)(p.proj + (size_t)NTOK * D + (size_t)tok * D);
  float4 xv0 = xr[lane], xv1 = xr[lane + 64];
  float4 pa0 = p0r[lane], pa1 = p0r[lane + 64];
  float4 pb0 = p1r[lane], pb1 = p1r[lane + 64];
  float pe[8], xe[8];
  xe[0]=xv0.x; xe[1]=xv0.y; xe[2]=xv0.z; xe[3]=xv0.w; xe[4]=xv1.x; xe[5]=xv1.y; xe[6]=xv1.z; xe[7]=xv1.w;
  pe[0]=pa0.x+pb0.x; pe[1]=pa0.y+pb0.y; pe[2]=pa0.z+pb0.z; pe[3]=pa0.w+pb0.w;
  pe[4]=pa1.x+pb1.x; pe[5]=pa1.y+pb1.y; pe[6]=pa1.z+pb1.z; pe[7]=pa1.w+pb1.w;
  double sx = 0, sp = 0, xx = 0, pp = 0, xp = 0;
#pragma unroll
  for (int j = 0; j < 8; ++j) {
    double dx = xe[j], dp = pe[j];
    sx += dx; sp += dp; xx += dx * dx; pp += dp * dp; xp += dx * dp;
  }
  sx = wave_sum(sx); sp = wave_sum(sp); xx = wave_sum(xx);
  pp = wave_sum(pp); xp = wave_sum(xp);
  double c = (double)p.cgl[0];
  double sc = sqrt(c); if (sc < EPSd) sc = EPSd;
  double pn = sqrt(pp);
  double me = tanh(sc * fmax(pn, EPSd)) / sc;
  double fs = (pn < EPSd) ? 0.0 : me / fmax(pn, EPSd);
  if (me >= 1.0) fs *= (1.0 - EPSd) / me;
  double y2 = fs * fs * pp, xy = fs * xp;
  double a = 1.0 + 2.0 * c * xy + c * y2;
  double b = 1.0 - c * xx;
  double den = 1.0 + 2.0 * c * xy + c * c * xx * y2;
  if (den < EPSd) den = EPSd;
  double zn = sqrt(fmax(a * a * xx + 2.0 * a * b * xy + b * b * y2, 0.0)) / den;
  double zs = 1.0 / den;
  if (zn >= 1.0) zs *= (1.0 - EPSd) / zn;
  double xan = (zn >= 1.0) ? (1.0 - EPSd) : zn;
  double A0 = zs * a, B0 = zs * b * fs;
  double xav[8];
#pragma unroll
  for (int j = 0; j < 8; ++j) xav[j] = A0 * (double)xe[j] + B0 * (double)pe[j];
  {
    float4 o0 = {(float)xav[0], (float)xav[1], (float)xav[2], (float)xav[3]};
    float4 o1 = {(float)xav[4], (float)xav[5], (float)xav[6], (float)xav[7]};
    float4* xw = (float4*)(p.xa + (size_t)tok * D);
    xw[lane] = o0; xw[lane + 64] = o1;
  }
  double sxa  = A0 * sx + B0 * sp;
  double sxa2 = A0 * A0 * xx + 2.0 * A0 * B0 * xp + B0 * B0 * pp;
  double fl = 0.0;
  if (xan >= EPSd) fl = atanh(fmin(xan, 1.0 - EPSd)) / (sc * fmax(xan, EPSd));
  double mu = fl * sxa / D;
  double var = fl * fl * sxa2 / D - mu * mu;
  double rs = 1.0 / sqrt(var + 1e-6);
  const float4* s2r = (const float4*)p.s2;
  const float4* b2r = (const float4*)p.b2;
  float4 sA = s2r[lane], sB = s2r[lane + 64];
  float4 bA = b2r[lane], bB = b2r[lane + 64];
  const float se[8] = {sA.x, sA.y, sA.z, sA.w, sB.x, sB.y, sB.z, sB.w};
  const float be[8] = {bA.x, bA.y, bA.z, bA.w, bB.x, bB.y, bB.z, bB.w};
  double w[8]; double sww = 0.0;
#pragma unroll
  for (int j = 0; j < 8; ++j) {
    w[j] = (fl * xav[j] - mu) * rs * (double)se[j] + (double)be[j];
    sww += w[j] * w[j];
  }
  sww = wave_sum(sww);
  double vn = sqrt(sww);
  double F = 0.0;
  if (vn >= EPSd) {
    double mag_e = tanh(sc * fmax(vn, EPSd)) / sc;
    F = atanh(fmin(mag_e, 1.0 - EPSd)) / (sc * vn);
  }
  h16* dst = p.t2 + (size_t)tok * D;
#pragma unroll
  for (int half = 0; half < 2; ++half) {
    h4v o;
#pragma unroll
    for (int e = 0; e < 4; ++e) o[e] = (h16)(float)(F * w[half * 4 + e]);
    *(h4v*)(dst + 4 * (lane + 64 * half)) = o;
  }
}

// ---------------- final: expmap0(ffn) -> mobius add -> out; one WAVE per row ----------------
DEV void do_final(int pb, const KParams& p) {
  const int wid = threadIdx.x >> 6, lane = threadIdx.x & 63;
  const int tok = pb * 4 + wid;
  const float4* ar  = (const float4*)(p.xa + (size_t)tok * D);
  const float4* f0r = (const float4*)(p.f2 + (size_t)tok * D);
  const float4* f1r = (const float4*)(p.f2 + (size_t)NTOK * D + (size_t)tok * D);
  float4 xv0 = ar[lane], xv1 = ar[lane + 64];
  float4 pa0 = f0r[lane], pa1 = f0r[lane + 64];
  float4 pb0 = f1r[lane], pb1 = f1r[lane + 64];
  float pe[8], xe[8];
  xe[0]=xv0.x; xe[1]=xv0.y; xe[2]=xv0.z; xe[3]=xv0.w; xe[4]=xv1.x; xe[5]=xv1.y; xe[6]=xv1.z; xe[7]=xv1.w;
  pe[0]=pa0.x+pb0.x; pe[1]=pa0.y+pb0.y; pe[2]=pa0.z+pb0.z; pe[3]=pa0.w+pb0.w;
  pe[4]=pa1.x+pb1.x; pe[5]=pa1.y+pb1.y; pe[6]=pa1.z+pb1.z; pe[7]=pa1.w+pb1.w;
  double xx = 0, pp = 0, xp = 0;
#pragma unroll
  for (int j = 0; j < 8; ++j) {
    double dx = xe[j], dp = pe[j];
    xx += dx * dx; pp += dp * dp; xp += dx * dp;
  }
  xx = wave_sum(xx); pp = wave_sum(pp); xp = wave_sum(xp);
  double c = (double)p.cgl[0];
  double sc = sqrt(c); if (sc < EPSd) sc = EPSd;
  double pn = sqrt(pp);
  double me = tanh(sc * fmax(pn, EPSd)) / sc;
  double fs = (pn < EPSd) ? 0.0 : me / fmax(pn, EPSd);
  if (me >= 1.0) fs *= (1.0 - EPSd) / me;
  double y2 = fs * fs * pp, xy = fs * xp;
  double a = 1.0 + 2.0 * c * xy + c * y2;
  double b = 1.0 - c * xx;
  double den = 1.0 + 2.0 * c * xy + c * c * xx * y2;
  if (den < EPSd) den = EPSd;
  double zn = sqrt(fmax(a * a * xx + 2.0 * a * b * xy + b * b * y2, 0.0)) / den;
  double zs = 1.0 / den;
  if (zn >= 1.0) zs *= (1.0 - EPSd) / zn;
  double A0 = zs * a, B0 = zs * b * fs;
  float4 o0, o1;
  o0.x = (float)(A0 * xe[0] + B0 * pe[0]); o0.y = (float)(A0 * xe[1] + B0 * pe[1]);
  o0.z = (float)(A0 * xe[2] + B0 * pe[2]); o0.w = (float)(A0 * xe[3] + B0 * pe[3]);
  o1.x = (float)(A0 * xe[4] + B0 * pe[4]); o1.y = (float)(A0 * xe[5] + B0 * pe[5]);
  o1.z = (float)(A0 * xe[6] + B0 * pe[6]); o1.w = (float)(A0 * xe[7] + B0 * pe[7]);
  float4* ow = (float4*)(p.out + (size_t)tok * D);
  ow[lane] = o0; ow[lane + 64] = o1;
}

// ---------------- the fused persistent cooperative kernel (256 blocks = 1/CU) ---------------
__global__ __launch_bounds__(256, 2) void k_all(KParams p) {
  __shared__ __align__(16) char SM[49152];
  cg::grid_group grid = cg::this_grid();
  const int nb = gridDim.x;
  // P1: 4 weight transpose-casts (768) + pre (256) = 1024 tasks
  for (int t = blockIdx.x; t < 1024; t += nb) {
    __syncthreads();                 // LDS reuse guard between grid-stride iters
    if (t < 768) {
      const float* src; h16* dst; int K, N, bx, by, l;
      if (t < 192)      { l = t;       src = p.Wqkv; dst = p.WqkvT; K = 512;  N = 1536; bx = l % 24; by = l / 24; }
      else if (t < 256) { l = t - 192; src = p.Wout; dst = p.WoutT; K = 512;  N = 512;  bx = l % 8;  by = l / 8;  }
      else if (t < 512) { l = t - 256; src = p.Wff1; dst = p.Wff1T; K = 512;  N = 2048; bx = l % 32; by = l / 32; }
      else              { l = t - 512; src = p.Wff2; dst = p.Wff2T; K = 2048; N = 512;  bx = l % 8;  by = l / 8;  }
      tcast64(src, dst, K, N, bx * 64, by * 64, (float*)SM);
    } else {
      do_pre(t - 768, p);
    }
  }
  grid.sync();
  // P2: QKV GEMM, 24x16 = 384 tiles
  for (int t = blockIdx.x; t < 384; t += nb)
    mm_body<0, 1, 0>((h16*)SM, (h16*)(SM + 24576), p.xt, p.WqkvT, p.bqkv,
                     nullptr, p.qkv, NTOK, 1536, 512, t % 24, t / 24, 0);
  grid.sync();
  // P3: attention, 256 tasks
  for (int t = blockIdx.x; t < 256; t += nb) do_attn(t, p, SM);
  grid.sync();
  // P4: out-proj GEMM splitK=2, 8x16x2 = 256 tiles
  for (int t = blockIdx.x; t < 256; t += nb)
    mm_body<0, 0, 1>((h16*)SM, (h16*)(SM + 24576), p.ao, p.WoutT, p.bout,
                     p.proj, nullptr, NTOK, 512, 512, t % 8, (t >> 3) & 15, t >> 7);
  grid.sync();
  // P5: residual chain, 256 tasks
  for (int t = blockIdx.x; t < 256; t += nb) do_resid(t, p);
  grid.sync();
  // P6: FF1 GEMM (+GELU), 32x16 = 512 tiles
  for (int t = blockIdx.x; t < 512; t += nb)
    mm_body<1, 1, 0>((h16*)SM, (h16*)(SM + 24576), p.t2, p.Wff1T, p.bff1,
                     nullptr, p.h1, NTOK, 2048, 512, t % 32, t / 32, 0);
  grid.sync();
  // P7: FF2 GEMM splitK=2, 8x16x2 = 256 tiles
  for (int t = blockIdx.x; t < 256; t += nb)
    mm_body<0, 0, 1>((h16*)SM, (h16*)(SM + 24576), p.h1, p.Wff2T, p.bff2,
                     p.f2, nullptr, NTOK, 512, 2048, t % 8, (t >> 3) & 15, t >> 7);
  grid.sync();
  // P8: final mobius residual, 256 tasks
  for (int t = blockIdx.x; t < 256; t += nb) do_final(t, p);
}

// ---------------- launch ----------------
extern "C" void kernel_launch(void* const* d_in, const int* in_sizes, int n_in,
                              void* d_out, int out_size, void* d_ws, size_t ws_size,
                              hipStream_t stream) {
  (void)in_sizes; (void)n_in; (void)out_size; (void)ws_size;
  char* base = (char*)d_ws;
  const size_t MB = 1024 * 1024;
  KParams p;
  p.x    = (const float*)d_in[0];
  p.cgl  = (const float*)d_in[1];
  p.Wqkv = (const float*)d_in[2];
  p.bqkv = (const float*)d_in[3];
  p.Wout = (const float*)d_in[4];
  p.bout = (const float*)d_in[5];
  p.s1   = (const float*)d_in[6];
  p.b1   = (const float*)d_in[7];
  p.s2   = (const float*)d_in[8];
  p.b2   = (const float*)d_in[9];
  p.Wff1 = (const float*)d_in[10];
  p.bff1 = (const float*)d_in[11];
  p.Wff2 = (const float*)d_in[12];
  p.bff2 = (const float*)d_in[13];
  p.chl  = (const float*)d_in[14];
  p.geo  = (const float*)d_in[15];
  p.out  = (float*)d_out;
  // workspace layout (lifetime-overlaid, peak 15 MB) — same plan as the 8-dispatch version
  p.WqkvT = (h16*)(base + 0);             // 1.5 [P1 .. P2]
  p.WoutT = (h16*)(base + (3 * MB) / 2);  // 0.5 [P1 .. P4]
  p.Wff1T = (h16*)(base + 2 * MB);        // 2   [P1 .. P6]
  p.Wff2T = (h16*)(base + 4 * MB);        // 2   [P1 .. P7]
  p.xt    = (h16*)(base + 6 * MB);        // 1   [P1 .. P2]
  p.qkv   = (h16*)(base + 7 * MB);        // 3   [P2 .. P3]
  p.ao    = (h16*)(base + 10 * MB);       // 1   [P3 .. P4]
  p.proj  = (float*)(base + 11 * MB);     // 4   [P4 .. P5] (2 split-K pieces)
  p.xa    = (float*)(base + 7 * MB);      // 2   [P5 .. P8] (qkv slot, dead)
  p.t2    = (h16*)(base + 6 * MB);        // 1   [P5 .. P6] (xt slot)
  p.h1    = (h16*)(base + 11 * MB);       // 4   [P6 .. P7] (proj slot, dead)
  p.f2    = (float*)(base + 0);           // 4   [P7 .. P8] (WqkvT/WoutT/Wff1T slots, dead)

  void* args[] = {&p};
  hipLaunchCooperativeKernel((void*)k_all, dim3(256), dim3(256), args, 0, stream);
}

// Round 14
// 68.732 us; speedup vs baseline: 3.7111x; 3.7111x over previous
//
#include <hip/hip_runtime.h>
#include <math.h>

#define DEV __device__ __forceinline__
typedef _Float16 h16;
typedef __attribute__((ext_vector_type(8))) _Float16 h8v;  // 8 fp16 = 4 VGPR
typedef __attribute__((ext_vector_type(4))) _Float16 h4v;  // 8-byte fp16 store
typedef __attribute__((ext_vector_type(4))) float f4v;

constexpr int NTOK = 1024;
constexpr int D    = 512;
constexpr int H    = 8;
constexpr int NB   = 16;
constexpr double EPSd = 1e-7;

// ---------------- wave reduction (row fully owned by one wave; no barriers) ----------------
DEV double wave_sum(double v) {
#pragma unroll
  for (int m = 32; m; m >>= 1) v += __shfl_xor(v, m, 64);
  return v;
}

// ---------------- 64x64 transpose-cast tile: fp32[K][N] -> fp16[N][K] ----------------
// float4 global loads, float4 LDS writes, h4v (8B) coalesced stores.
DEV void tcast64(const float* __restrict__ src, h16* __restrict__ dst,
                 int K, int N, int n0, int k0, float* tls /* [64*68] */) {
  const int tx = threadIdx.x & 15, ty = threadIdx.x >> 4;
#pragma unroll
  for (int it = 0; it < 4; ++it) {
    const int k = ty + it * 16;
    float4 v = *(const float4*)(src + (size_t)(k0 + k) * N + n0 + tx * 4);
    *(float4*)(tls + k * 68 + tx * 4) = v;
  }
  __syncthreads();
#pragma unroll
  for (int it = 0; it < 4; ++it) {
    const int n = ty + it * 16;
    const int kc = tx * 4;
    h4v o;
#pragma unroll
    for (int j = 0; j < 4; ++j) o[j] = (h16)tls[(kc + j) * 68 + n];
    *(h4v*)(dst + (size_t)(n0 + n) * K + k0 + kc) = o;
  }
}

// ---------------- k_prep: Wqkv transpose (192 blocks) + pre (256 blocks) ----------------
__global__ void k_prep(const float* __restrict__ Wqkv,
                       const float* __restrict__ x, const float* __restrict__ cg,
                       const float* __restrict__ s1, const float* __restrict__ b1,
                       h16* __restrict__ qT, h16* __restrict__ xt) {
  __shared__ __align__(16) float tls[64 * 68];
  const int bid = blockIdx.x;
  if (bid < 192) {    // Wqkv: K=512, N=1536 -> 24 x 8 tiles
    tcast64(Wqkv, qT, 512, 1536, (bid % 24) * 64, (bid / 24) * 64, tls);
    return;
  }
  // ---- pre: logmap0 -> LN -> expmap0 -> logmap0 (fused), one WAVE per token row ----
  const int wid = threadIdx.x >> 6, lane = threadIdx.x & 63;
  const int tok = (bid - 192) * 4 + wid;
  const float4* xr = (const float4*)(x + (size_t)tok * D);
  float4 xv0 = xr[lane], xv1 = xr[lane + 64];
  double sv = 0.0, svv = 0.0;
  {
    const float e[8] = {xv0.x, xv0.y, xv0.z, xv0.w, xv1.x, xv1.y, xv1.z, xv1.w};
#pragma unroll
    for (int j = 0; j < 8; ++j) { double d = e[j]; sv += d; svv += d * d; }
  }
  sv = wave_sum(sv); svv = wave_sum(svv);
  double c = (double)cg[0];
  double sc = sqrt(c); if (sc < EPSd) sc = EPSd;
  double yn = sqrt(svv);
  double arg0 = yn; if (arg0 > 1.0 - EPSd) arg0 = 1.0 - EPSd;
  double f = (yn < EPSd) ? 0.0 : atanh(arg0) / sc / fmax(yn, EPSd);
  double mu = f * sv / D;
  double var = f * f * svv / D - mu * mu;
  double rs = 1.0 / sqrt(var + 1e-6);
  const float4* s1r = (const float4*)s1;
  const float4* b1r = (const float4*)b1;
  float4 sA = s1r[lane], sB = s1r[lane + 64];
  float4 bA = b1r[lane], bB = b1r[lane + 64];
  double w[8]; double sww = 0.0;
  {
    const float e[8]  = {xv0.x, xv0.y, xv0.z, xv0.w, xv1.x, xv1.y, xv1.z, xv1.w};
    const float se[8] = {sA.x, sA.y, sA.z, sA.w, sB.x, sB.y, sB.z, sB.w};
    const float be[8] = {bA.x, bA.y, bA.z, bA.w, bB.x, bB.y, bB.z, bB.w};
#pragma unroll
    for (int j = 0; j < 8; ++j) {
      w[j] = (f * (double)e[j] - mu) * rs * (double)se[j] + (double)be[j];
      sww += w[j] * w[j];
    }
  }
  sww = wave_sum(sww);
  double vn = sqrt(sww);
  double F = 0.0;
  if (vn >= EPSd) {
    double mag_e = tanh(sc * fmax(vn, EPSd)) / sc;
    F = atanh(fmin(mag_e, 1.0 - EPSd)) / (sc * vn);
  }
  h16* dst = xt + (size_t)tok * D;
#pragma unroll
  for (int half = 0; half < 2; ++half) {
    h4v o;
#pragma unroll
    for (int e = 0; e < 4; ++e) o[e] = (h16)(float)(F * w[half * 4 + e]);
    *(h4v*)(dst + 4 * (lane + 64 * half)) = o;
  }
}

// ---------------- fp16 MFMA GEMM, 64x64 tile, BK=64, 3-deep counted-vmcnt pipeline ----------
// LDS content chunk c of row r stored at chunk position c^(r&7) (pre-swizzled GLOBAL source;
// global_load_lds dest is linear base + lane*16). Reads apply the same XOR.
DEV void stage_tile(const h16* __restrict__ gbase, int rowstride, h16* lds,
                    int wid, int lane) {
#pragma unroll
  for (int j = 0; j < 2; ++j) {
    const int rbase = wid * 16 + j * 8;
    const int grow = rbase + (lane >> 3);
    const int gch = (lane & 7) ^ (lane >> 3);
    const h16* gp = gbase + (size_t)grow * rowstride + gch * 8;
    __builtin_amdgcn_global_load_lds(
        (const __attribute__((address_space(1))) void*)gp,
        (__attribute__((address_space(3))) void*)(lds + rbase * 64), 16, 0, 0);
  }
}
DEV h8v read_frag(const h16* lds, int row, int c) {
  const int p = c ^ (row & 7);
  return *(const h8v*)(lds + row * 64 + p * 8);
}

// SPLITK: grid.z pieces over K; piece z writes Cf + z*M*N (fp32), bias only in piece 0.
template <int GELU, int OHALF, int SPLITK>
__global__ __launch_bounds__(256) void k_mm(
    const h16* __restrict__ A, const h16* __restrict__ B,
    const float* __restrict__ bias, float* __restrict__ Cf, h16* __restrict__ Ch,
    int M, int N, int K) {
  __shared__ __align__(16) h16 As[3][64 * 64];
  __shared__ __align__(16) h16 Bs[3][64 * 64];
  const int tid = threadIdx.x;
  const int lane = tid & 63, wid = tid >> 6;
  const int wr = (wid >> 1) * 32, wc = (wid & 1) * 32;
  const int lr = lane & 15, lg = lane >> 4;
  const size_t r0 = (size_t)blockIdx.y * 64, c0 = (size_t)blockIdx.x * 64;
  const int kz = SPLITK ? blockIdx.z : 0;
  const int Keff = SPLITK ? (K >> 1) : K;
  const f4v z = {0.f, 0.f, 0.f, 0.f};
  f4v acc[2][2]; acc[0][0] = z; acc[0][1] = z; acc[1][0] = z; acc[1][1] = z;
  const h16* Abase = A + r0 * K + (size_t)kz * Keff;
  const h16* Bbase = B + c0 * K + (size_t)kz * Keff;
  const int NT = Keff >> 6;
  // Preload bias NOW and drain vmcnt to 0 so the K-loop's counted waits are exact
  // regardless of where the compiler would otherwise place this loop-invariant load.
  const size_t col0 = c0 + wc + lr;
  float bv0 = bias[col0];
  float bv1 = bias[col0 + 16];
  asm volatile("" :: "v"(bv0), "v"(bv1));             // force loads issued here
  asm volatile("s_waitcnt vmcnt(0)" ::: "memory");    // zero outstanding VMEM
  if (SPLITK && kz) { bv0 = 0.f; bv1 = 0.f; }
  // prologue: tiles 0,1 in flight (8 loads/wave)
  stage_tile(Abase, K, As[0], wid, lane);
  stage_tile(Bbase, K, Bs[0], wid, lane);
  stage_tile(Abase + 64, K, As[1], wid, lane);
  stage_tile(Bbase + 64, K, Bs[1], wid, lane);
  int cur = 0;
  for (int t = 0; t < NT; ++t) {
    const int pre = (cur == 2) ? 0 : cur + 1;      // buf for t+2 = (cur+2)%3
    const int pre2 = (pre == 2) ? 0 : pre + 1;
    if (t + 2 < NT) {                      // keep 2 tiles in flight
      stage_tile(Abase + (t + 2) * 64, K, As[pre2], wid, lane);
      stage_tile(Bbase + (t + 2) * 64, K, Bs[pre2], wid, lane);
    }
    const int rem = NT - 1 - t;
    if (rem >= 2)      asm volatile("s_waitcnt vmcnt(8)" ::: "memory");
    else if (rem == 1) asm volatile("s_waitcnt vmcnt(4)" ::: "memory");
    else               asm volatile("s_waitcnt vmcnt(0)" ::: "memory");
    asm volatile("s_barrier" ::: "memory");             // all waves' cur loads landed
    const h16* Ac = As[cur];
    const h16* Bc = Bs[cur];
#pragma unroll
    for (int ks = 0; ks < 2; ++ks) {
      const int c = ks * 4 + lg;
      h8v a0 = read_frag(Ac, wr + lr, c);
      h8v a1 = read_frag(Ac, wr + 16 + lr, c);
      h8v b0 = read_frag(Bc, wc + lr, c);
      h8v b1 = read_frag(Bc, wc + 16 + lr, c);
      acc[0][0] = __builtin_amdgcn_mfma_f32_16x16x32_f16(a0, b0, acc[0][0], 0, 0, 0);
      acc[0][1] = __builtin_amdgcn_mfma_f32_16x16x32_f16(a0, b1, acc[0][1], 0, 0, 0);
      acc[1][0] = __builtin_amdgcn_mfma_f32_16x16x32_f16(a1, b0, acc[1][0], 0, 0, 0);
      acc[1][1] = __builtin_amdgcn_mfma_f32_16x16x32_f16(a1, b1, acc[1][1], 0, 0, 0);
    }
    // LDS reads retire into regs before MFMA (compiler lgkmcnt); barrier ends the iter.
    asm volatile("s_barrier" ::: "memory");
    cur = pre;
  }
  float* Cfo = Cf + (size_t)kz * M * N;
#pragma unroll
  for (int m = 0; m < 2; ++m)
#pragma unroll
    for (int n = 0; n < 2; ++n) {
      const size_t row = r0 + wr + m * 16 + lg * 4;
      const size_t col = col0 + n * 16;
      const float bv = n ? bv1 : bv0;
#pragma unroll
      for (int e = 0; e < 4; ++e) {
        float v = acc[m][n][e] + bv;
        if (GELU) {
          float x3 = v * v * v;
          v = 0.5f * v * (1.0f + tanhf(0.7978845608028654f * (v + 0.044715f * x3)));
        }
        if (OHALF) Ch[(row + e) * N + col] = (h16)v;
        else       Cfo[(row + e) * N + col] = v;
      }
    }
}

// ---------------- attention (256 blocks) + deferred Wout/Wff1/Wff2 transposes (576) --------
// Attn: 2 blocks per (be,h): each owns 32 q-rows (8 lanes/row, 8 cols each). K/V staged fully.
// Vectorized h8v staging; row norms computed from RAW q/k (RoPE rotation is orthogonal).
__global__ __launch_bounds__(256) void k_attn(
    const h16* __restrict__ qkv, const float* __restrict__ chl,
    const float* __restrict__ geo, h16* __restrict__ ao,
    const float* __restrict__ Wo, const float* __restrict__ Wf1,
    const float* __restrict__ Wf2,
    h16* __restrict__ oT, h16* __restrict__ f1T, h16* __restrict__ f2T) {
  __shared__ __align__(16) float Qs[32][68];
  __shared__ __align__(16) float Kt[64][68];   // K transposed: Kt[d][s]; tcast tls alias
  __shared__ __align__(16) float Vs[64][68];
  __shared__ float q2raw[32], k2raw[64];
  __shared__ float q2s[32], k2s[64], fqv[32], fkv[64];
  const int bid = blockIdx.x;
  if (bid >= 256) {   // ---- deferred transpose-casts on otherwise-idle CUs ----
    const float* src; h16* dst; int K, N, bx, by, l;
    if (bid < 320)      { l = bid - 256; src = Wo;  dst = oT;  K = 512;  N = 512;  bx = l % 8;  by = l / 8;  }
    else if (bid < 576) { l = bid - 320; src = Wf1; dst = f1T; K = 512;  N = 2048; bx = l % 32; by = l / 32; }
    else                { l = bid - 576; src = Wf2; dst = f2T; K = 2048; N = 512;  bx = l % 8;  by = l / 8;  }
    tcast64(src, dst, K, N, bx * 64, by * 64, &Kt[0][0]);
    return;
  }
  const int be = bid >> 4, h = (bid >> 1) & 7, q0 = (bid & 1) * 32;
  const int tid = threadIdx.x;
  const double chd = log1p(exp((double)chl[h]));   // softplus (once)
  const float ch = (float)chd;
  float sc = (float)sqrt(chd); if (sc < 1e-7f) sc = 1e-7f;
  // ---- stage K^T (RoPE) + V, 64 rows; 256 tasks = (s, 8-wide j-chunk) ----
  {
    const int s = tid >> 2, jc = (tid & 3) * 8;
    const h16* base = qkv + (size_t)(be * 64 + s) * 1536 + h * 64;
    h8v klo = *(const h8v*)(base + 512 + jc);
    h8v khi = *(const h8v*)(base + 512 + jc + 32);
    h8v vlo = *(const h8v*)(base + 1024 + jc);
    h8v vhi = *(const h8v*)(base + 1024 + jc + 32);
    float racc = 0.f;
#pragma unroll
    for (int j = 0; j < 8; ++j) {
      float ka = (float)klo[j], kb = (float)khi[j];
      racc += ka * ka + kb * kb;
      float fj = expf((float)(jc + j) * -0.2878231366242557f);   // ln(10000)/32
      float st, ct; sincosf((float)s * fj, &st, &ct);
      Kt[jc + j][s]      = ka * ct - kb * st;
      Kt[jc + j + 32][s] = ka * st + kb * ct;
    }
    float4 v0, v1;
#pragma unroll
    for (int j = 0; j < 4; ++j) { v0[j] = (float)vlo[j]; v1[j] = (float)vlo[j + 4]; }
    *(float4*)&Vs[s][jc] = v0; *(float4*)&Vs[s][jc + 4] = v1;
#pragma unroll
    for (int j = 0; j < 4; ++j) { v0[j] = (float)vhi[j]; v1[j] = (float)vhi[j + 4]; }
    *(float4*)&Vs[s][jc + 32] = v0; *(float4*)&Vs[s][jc + 36] = v1;
    racc += __shfl_xor(racc, 1, 64);
    racc += __shfl_xor(racc, 2, 64);
    if ((tid & 3) == 0) k2raw[s] = racc;
  }
  // ---- stage Q (RoPE), 32 rows; 128 tasks ----
  if (tid < 128) {
    const int s = tid >> 2, jc = (tid & 3) * 8;
    const h16* base = qkv + (size_t)(be * 64 + q0 + s) * 1536 + h * 64;
    h8v qlo = *(const h8v*)(base + jc);
    h8v qhi = *(const h8v*)(base + jc + 32);
    float racc = 0.f;
    float rl[8], rh[8];
#pragma unroll
    for (int j = 0; j < 8; ++j) {
      float qa = (float)qlo[j], qb = (float)qhi[j];
      racc += qa * qa + qb * qb;
      float fj = expf((float)(jc + j) * -0.2878231366242557f);
      float st, ct; sincosf((float)(q0 + s) * fj, &st, &ct);
      rl[j] = qa * ct - qb * st;
      rh[j] = qa * st + qb * ct;
    }
    *(float4*)&Qs[s][jc]      = {rl[0], rl[1], rl[2], rl[3]};
    *(float4*)&Qs[s][jc + 4]  = {rl[4], rl[5], rl[6], rl[7]};
    *(float4*)&Qs[s][jc + 32] = {rh[0], rh[1], rh[2], rh[3]};
    *(float4*)&Qs[s][jc + 36] = {rh[4], rh[5], rh[6], rh[7]};
    racc += __shfl_xor(racc, 1, 64);
    racc += __shfl_xor(racc, 2, 64);
    if ((tid & 3) == 0) q2raw[s] = racc;
  }
  __syncthreads();
  // ---- per-row expmap0 factors from raw norms ----
  if (tid < 64) {
    float n = sqrtf(k2raw[tid]);
    float m = tanhf(sc * fmaxf(n, 1e-7f)) / sc;
    float f = (n < 1e-7f) ? 0.f : m / fmaxf(n, 1e-7f);
    if (m >= 1.f) f *= (1.f - 1e-7f) / m;
    float fn = f * n;
    fkv[tid] = f; k2s[tid] = fn * fn;
  } else if (tid < 96) {
    int i = tid - 64;
    float n = sqrtf(q2raw[i]);
    float m = tanhf(sc * fmaxf(n, 1e-7f)) / sc;
    float f = (n < 1e-7f) ? 0.f : m / fmaxf(n, 1e-7f);
    if (m >= 1.f) f *= (1.f - 1e-7f) / m;
    float fn = f * n;
    fqv[i] = f; q2s[i] = fn * fn;
  }
  __syncthreads();
  const int i = tid >> 3, g = tid & 7;   // local q-row, 8-col group
  float gacc[8];
#pragma unroll
  for (int jj = 0; jj < 8; ++jj) gacc[jj] = 0.f;
  for (int d2 = 0; d2 < 64; ++d2) {
    float qv = Qs[i][d2];
    const float4* kp = (const float4*)&Kt[d2][g * 8];
    float4 k0 = kp[0], k1 = kp[1];
    gacc[0] += qv * k0.x; gacc[1] += qv * k0.y; gacc[2] += qv * k0.z; gacc[3] += qv * k0.w;
    gacc[4] += qv * k1.x; gacc[5] += qv * k1.y; gacc[6] += qv * k1.z; gacc[7] += qv * k1.w;
  }
  const float gs = geo[h];
  const float q2 = q2s[i], fqi = fqv[i];
  float lg[8];
  float mx = -1e30f;
#pragma unroll
  for (int jj = 0; jj < 8; ++jj) {
    float gq = fqi * fkv[g * 8 + jj] * gacc[jj];
    float k2 = k2s[g * 8 + jj];
    float A  = 1.f - 2.f * ch * gq + ch * k2;
    float Bv = 1.f - ch * q2;
    float n2 = fmaxf(A * A * q2 - 2.f * A * Bv * gq + Bv * Bv * k2, 0.f);
    float den = fmaxf(1.f - 2.f * ch * gq + ch * ch * q2 * k2, 1e-7f);
    float r = fminf(sqrtf(n2) / den, 1.f - 1e-7f);
    float arg = fminf(sc * r, 1.f - 1e-7f);
    float l = -gs * (2.f * atanhf(arg) / sc);
    lg[jj] = l; mx = fmaxf(mx, l);
  }
  mx = fmaxf(mx, __shfl_xor(mx, 1, 64));
  mx = fmaxf(mx, __shfl_xor(mx, 2, 64));
  mx = fmaxf(mx, __shfl_xor(mx, 4, 64));
  float pv[8]; float sum = 0.f;
#pragma unroll
  for (int jj = 0; jj < 8; ++jj) { pv[jj] = expf(lg[jj] - mx); sum += pv[jj]; }
  sum += __shfl_xor(sum, 1, 64);
  sum += __shfl_xor(sum, 2, 64);
  sum += __shfl_xor(sum, 4, 64);
  float inv = 1.0f / sum;
  // P overwrite of Qs: wave w owns rows 8w..8w+7 exclusively; in-wave lockstep
  // guarantees all lanes finished reading row i before any lane stores.
#pragma unroll
  for (int jj = 0; jj < 8; ++jj) Qs[i][g * 8 + jj] = pv[jj] * inv;
  float oacc[8];
#pragma unroll
  for (int dd = 0; dd < 8; ++dd) oacc[dd] = 0.f;
  for (int jv = 0; jv < 64; ++jv) {
    float p = Qs[i][jv];
    const float4* vp = (const float4*)&Vs[jv][g * 8];
    float4 v0 = vp[0], v1 = vp[1];
    oacc[0] += p * v0.x; oacc[1] += p * v0.y; oacc[2] += p * v0.z; oacc[3] += p * v0.w;
    oacc[4] += p * v1.x; oacc[5] += p * v1.y; oacc[6] += p * v1.z; oacc[7] += p * v1.w;
  }
  h8v ov;
#pragma unroll
  for (int dd = 0; dd < 8; ++dd) ov[dd] = (h16)oacc[dd];
  *(h8v*)(ao + (size_t)(be * 64 + q0 + i) * D + h * 64 + g * 8) = ov;
}

// ---------------- residual: expmap0(proj) -> mobius add -> LN2 chain; one WAVE per row -------
// proj arrives as TWO split-K partial buffers (piece stride NTOK*D), summed here.
__global__ void k_resid(const float* __restrict__ x, const float* __restrict__ proj,
                        const float* __restrict__ cg, const float* __restrict__ s2,
                        const float* __restrict__ b2, float* __restrict__ xa,
                        h16* __restrict__ t2) {
  const int wid = threadIdx.x >> 6, lane = threadIdx.x & 63;
  const int tok = blockIdx.x * 4 + wid;
  const float4* xr  = (const float4*)(x + (size_t)tok * D);
  const float4* p0r = (const float4*)(proj + (size_t)tok * D);
  const float4* p1r = (const float4*)(proj + (size_t)NTOK * D + (size_t)tok * D);
  float4 xv0 = xr[lane], xv1 = xr[lane + 64];
  float4 pa0 = p0r[lane], pa1 = p0r[lane + 64];
  float4 pb0 = p1r[lane], pb1 = p1r[lane + 64];
  float pe[8], xe[8];
  xe[0]=xv0.x; xe[1]=xv0.y; xe[2]=xv0.z; xe[3]=xv0.w; xe[4]=xv1.x; xe[5]=xv1.y; xe[6]=xv1.z; xe[7]=xv1.w;
  pe[0]=pa0.x+pb0.x; pe[1]=pa0.y+pb0.y; pe[2]=pa0.z+pb0.z; pe[3]=pa0.w+pb0.w;
  pe[4]=pa1.x+pb1.x; pe[5]=pa1.y+pb1.y; pe[6]=pa1.z+pb1.z; pe[7]=pa1.w+pb1.w;
  double sx = 0, sp = 0, xx = 0, pp = 0, xp = 0;
#pragma unroll
  for (int j = 0; j < 8; ++j) {
    double dx = xe[j], dp = pe[j];
    sx += dx; sp += dp; xx += dx * dx; pp += dp * dp; xp += dx * dp;
  }
  sx = wave_sum(sx); sp = wave_sum(sp); xx = wave_sum(xx);
  pp = wave_sum(pp); xp = wave_sum(xp);
  double c = (double)cg[0];
  double sc = sqrt(c); if (sc < EPSd) sc = EPSd;
  double pn = sqrt(pp);
  double me = tanh(sc * fmax(pn, EPSd)) / sc;
  double fs = (pn < EPSd) ? 0.0 : me / fmax(pn, EPSd);
  if (me >= 1.0) fs *= (1.0 - EPSd) / me;
  double y2 = fs * fs * pp, xy = fs * xp;
  double a = 1.0 + 2.0 * c * xy + c * y2;
  double b = 1.0 - c * xx;
  double den = 1.0 + 2.0 * c * xy + c * c * xx * y2;
  if (den < EPSd) den = EPSd;
  double zn = sqrt(fmax(a * a * xx + 2.0 * a * b * xy + b * b * y2, 0.0)) / den;
  double zs = 1.0 / den;
  if (zn >= 1.0) zs *= (1.0 - EPSd) / zn;
  double xan = (zn >= 1.0) ? (1.0 - EPSd) : zn;
  double A0 = zs * a, B0 = zs * b * fs;
  double xav[8];
#pragma unroll
  for (int j = 0; j < 8; ++j) xav[j] = A0 * (double)xe[j] + B0 * (double)pe[j];
  {
    float4 o0 = {(float)xav[0], (float)xav[1], (float)xav[2], (float)xav[3]};
    float4 o1 = {(float)xav[4], (float)xav[5], (float)xav[6], (float)xav[7]};
    float4* xw = (float4*)(xa + (size_t)tok * D);
    xw[lane] = o0; xw[lane + 64] = o1;
  }
  double sxa  = A0 * sx + B0 * sp;
  double sxa2 = A0 * A0 * xx + 2.0 * A0 * B0 * xp + B0 * B0 * pp;
  double fl = 0.0;
  if (xan >= EPSd) fl = atanh(fmin(xan, 1.0 - EPSd)) / (sc * fmax(xan, EPSd));
  double mu = fl * sxa / D;
  double var = fl * fl * sxa2 / D - mu * mu;
  double rs = 1.0 / sqrt(var + 1e-6);
  const float4* s2r = (const float4*)s2;
  const float4* b2r = (const float4*)b2;
  float4 sA = s2r[lane], sB = s2r[lane + 64];
  float4 bA = b2r[lane], bB = b2r[lane + 64];
  const float se[8] = {sA.x, sA.y, sA.z, sA.w, sB.x, sB.y, sB.z, sB.w};
  const float be[8] = {bA.x, bA.y, bA.z, bA.w, bB.x, bB.y, bB.z, bB.w};
  double w[8]; double sww = 0.0;
#pragma unroll
  for (int j = 0; j < 8; ++j) {
    w[j] = (fl * xav[j] - mu) * rs * (double)se[j] + (double)be[j];
    sww += w[j] * w[j];
  }
  sww = wave_sum(sww);
  double vn = sqrt(sww);
  double F = 0.0;
  if (vn >= EPSd) {
    double mag_e = tanh(sc * fmax(vn, EPSd)) / sc;
    F = atanh(fmin(mag_e, 1.0 - EPSd)) / (sc * vn);
  }
  h16* dst = t2 + (size_t)tok * D;
#pragma unroll
  for (int half = 0; half < 2; ++half) {
    h4v o;
#pragma unroll
    for (int e = 0; e < 4; ++e) o[e] = (h16)(float)(F * w[half * 4 + e]);
    *(h4v*)(dst + 4 * (lane + 64 * half)) = o;
  }
}

// ---------------- final: expmap0(ffn) -> mobius add -> out; one WAVE per row -------------
// f2 arrives as TWO split-K partial buffers, summed here.
__global__ void k_final(const float* __restrict__ xa, const float* __restrict__ f2,
                        const float* __restrict__ cg, float* __restrict__ out) {
  const int wid = threadIdx.x >> 6, lane = threadIdx.x & 63;
  const int tok = blockIdx.x * 4 + wid;
  const float4* ar  = (const float4*)(xa + (size_t)tok * D);
  const float4* f0r = (const float4*)(f2 + (size_t)tok * D);
  const float4* f1r = (const float4*)(f2 + (size_t)NTOK * D + (size_t)tok * D);
  float4 xv0 = ar[lane], xv1 = ar[lane + 64];
  float4 pa0 = f0r[lane], pa1 = f0r[lane + 64];
  float4 pb0 = f1r[lane], pb1 = f1r[lane + 64];
  float pe[8], xe[8];
  xe[0]=xv0.x; xe[1]=xv0.y; xe[2]=xv0.z; xe[3]=xv0.w; xe[4]=xv1.x; xe[5]=xv1.y; xe[6]=xv1.z; xe[7]=xv1.w;
  pe[0]=pa0.x+pb0.x; pe[1]=pa0.y+pb0.y; pe[2]=pa0.z+pb0.z; pe[3]=pa0.w+pb0.w;
  pe[4]=pa1.x+pb1.x; pe[5]=pa1.y+pb1.y; pe[6]=pa1.z+pb1.z; pe[7]=pa1.w+pb1.w;
  double xx = 0, pp = 0, xp = 0;
#pragma unroll
  for (int j = 0; j < 8; ++j) {
    double dx = xe[j], dp = pe[j];
    xx += dx * dx; pp += dp * dp; xp += dx * dp;
  }
  xx = wave_sum(xx); pp = wave_sum(pp); xp = wave_sum(xp);
  double c = (double)cg[0];
  double sc = sqrt(c); if (sc < EPSd) sc = EPSd;
  double pn = sqrt(pp);
  double me = tanh(sc * fmax(pn, EPSd)) / sc;
  double fs = (pn < EPSd) ? 0.0 : me / fmax(pn, EPSd);
  if (me >= 1.0) fs *= (1.0 - EPSd) / me;
  double y2 = fs * fs * pp, xy = fs * xp;
  double a = 1.0 + 2.0 * c * xy + c * y2;
  double b = 1.0 - c * xx;
  double den = 1.0 + 2.0 * c * xy + c * c * xx * y2;
  if (den < EPSd) den = EPSd;
  double zn = sqrt(fmax(a * a * xx + 2.0 * a * b * xy + b * b * y2, 0.0)) / den;
  double zs = 1.0 / den;
  if (zn >= 1.0) zs *= (1.0 - EPSd) / zn;
  double A0 = zs * a, B0 = zs * b * fs;
  float4 o0, o1;
  o0.x = (float)(A0 * xe[0] + B0 * pe[0]); o0.y = (float)(A0 * xe[1] + B0 * pe[1]);
  o0.z = (float)(A0 * xe[2] + B0 * pe[2]); o0.w = (float)(A0 * xe[3] + B0 * pe[3]);
  o1.x = (float)(A0 * xe[4] + B0 * pe[4]); o1.y = (float)(A0 * xe[5] + B0 * pe[5]);
  o1.z = (float)(A0 * xe[6] + B0 * pe[6]); o1.w = (float)(A0 * xe[7] + B0 * pe[7]);
  float4* ow = (float4*)(out + (size_t)tok * D);
  ow[lane] = o0; ow[lane + 64] = o1;
}

// ---------------- launch ----------------
extern "C" void kernel_launch(void* const* d_in, const int* in_sizes, int n_in,
                              void* d_out, int out_size, void* d_ws, size_t ws_size,
                              hipStream_t stream) {
  (void)in_sizes; (void)n_in; (void)out_size; (void)ws_size;
  const float* x    = (const float*)d_in[0];
  const float* cg   = (const float*)d_in[1];
  const float* Wqkv = (const float*)d_in[2];
  const float* bqkv = (const float*)d_in[3];
  const float* Wout = (const float*)d_in[4];
  const float* bout = (const float*)d_in[5];
  const float* s1   = (const float*)d_in[6];
  const float* b1   = (const float*)d_in[7];
  const float* s2   = (const float*)d_in[8];
  const float* b2   = (const float*)d_in[9];
  const float* Wff1 = (const float*)d_in[10];
  const float* bff1 = (const float*)d_in[11];
  const float* Wff2 = (const float*)d_in[12];
  const float* bff2 = (const float*)d_in[13];
  const float* chl  = (const float*)d_in[14];
  const float* geo  = (const float*)d_in[15];
  float* out = (float*)d_out;

  // ---- workspace layout (MB offsets), lifetime-overlaid; peak 15 MB ----
  char* base = (char*)d_ws;
  const size_t MB = 1024 * 1024;
  h16*   WqkvT = (h16*)(base + 0);            // 1.5 [prep .. qkv-mm]
  h16*   WoutT = (h16*)(base + (3*MB)/2);     // 0.5 [attn .. out-mm]
  h16*   Wff1T = (h16*)(base + 2*MB);         // 2   [attn .. ff1-mm]
  h16*   Wff2T = (h16*)(base + 4*MB);         // 2   [attn .. ff2-mm]
  h16*   xt    = (h16*)(base + 6*MB);         // 1   [prep .. qkv-mm]
  h16*   qkv   = (h16*)(base + 7*MB);         // 3   [qkv-mm .. attn]
  h16*   ao    = (h16*)(base + 10*MB);        // 1   [attn .. out-mm]
  float* proj  = (float*)(base + 11*MB);      // 4   [out-mm .. resid]   (2 split-K pieces)
  float* xa    = (float*)(base + 7*MB);       // 2   [resid .. final]    (qkv slot, dead)
  h16*   t2    = (h16*)(base + 6*MB);         // 1   [resid .. ff1-mm]   (xt slot)
  h16*   h1    = (h16*)(base + 11*MB);        // 4   [ff1-mm .. ff2-mm]  (proj slot, dead)
  float* f2    = (float*)(base + 0);          // 4   [ff2-mm .. final]   (W*T slots, dead)

  k_prep<<<192 + NTOK / 4, 256, 0, stream>>>(Wqkv, x, cg, s1, b1, WqkvT, xt);
  k_mm<0, 1, 0><<<dim3(1536 / 64, NTOK / 64), 256, 0, stream>>>(
      xt, WqkvT, bqkv, nullptr, qkv, NTOK, 1536, 512);
  k_attn<<<NB * H * 2 + 576, 256, 0, stream>>>(qkv, chl, geo, ao,
                                               Wout, Wff1, Wff2, WoutT, Wff1T, Wff2T);
  k_mm<0, 0, 1><<<dim3(512 / 64, NTOK / 64, 2), 256, 0, stream>>>(
      ao, WoutT, bout, proj, nullptr, NTOK, 512, 512);
  k_resid<<<NTOK / 4, 256, 0, stream>>>(x, proj, cg, s2, b2, xa, t2);
  k_mm<1, 1, 0><<<dim3(2048 / 64, NTOK / 64), 256, 0, stream>>>(
      t2, Wff1T, bff1, nullptr, h1, NTOK, 2048, 512);
  k_mm<0, 0, 1><<<dim3(512 / 64, NTOK / 64, 2), 256, 0, stream>>>(
      h1, Wff2T, bff2, f2, nullptr, NTOK, 512, 2048);
  k_final<<<NTOK / 4, 256, 0, stream>>>(xa, f2, cg, out);
}